// Round 7
// baseline (1486.923 us; speedup 1.0000x reference)
//
#include <hip/hip_runtime.h>
#include <math.h>

// Problem constants
constexpr int Bn = 64, Sn = 200, Cn = 32, Dn = 256, Vn = 10000, Tn = 1000;
constexpr int G3 = 3 * Dn; // 768

typedef __fp16 h2_t __attribute__((ext_vector_type(2)));
typedef short bf16x8 __attribute__((ext_vector_type(8)));
typedef float f32x4 __attribute__((ext_vector_type(4)));

static __device__ __forceinline__ h2_t as_h2(uint v) {
  union { uint u; h2_t h; } c; c.u = v; return c.h;
}
static __device__ __forceinline__ uint as_u32(h2_t h) {
  union { h2_t h; uint u; } c; c.h = h; return c.u;
}
static __device__ __forceinline__ ushort f2bf(float f) {  // RNE f32->bf16
  uint u = __float_as_uint(f);
  u += 0x7FFFu + ((u >> 16) & 1u);
  return (ushort)(u >> 16);
}

// ---------------------------------------------------------------------------
// Whh f32 -> packed f16 pairs (u32)
__global__ __launch_bounds__(256) void k_w2f16(const float* __restrict__ w,
    uint* __restrict__ o, int npairs) {
  int i = blockIdx.x * 256 + threadIdx.x;
  if (i < npairs) {
    h2_t pk = __builtin_amdgcn_cvt_pkrtz(w[2 * i], w[2 * i + 1]);
    o[i] = as_u32(pk);
  }
}

// f32 -> bf16 (ushort)
__global__ __launch_bounds__(256) void k_w2bf(const float* __restrict__ w,
    ushort* __restrict__ o, int n) {
  int i = blockIdx.x * 256 + threadIdx.x;
  if (i < n) o[i] = f2bf(w[i]);
}

// ---------------------------------------------------------------------------
// x[b,s,d] = sum_c emb[seqs[b,s,c]][d]; writes f32 and bf16
__global__ __launch_bounds__(256) void k_embed_sum(const int* __restrict__ seqs,
    const float* __restrict__ emb, float* __restrict__ x, ushort* __restrict__ xbf) {
  const int bs = blockIdx.x;
  const int d = threadIdx.x;
  const int* row = seqs + (size_t)bs * Cn;
  float acc = 0.f;
#pragma unroll
  for (int c = 0; c < Cn; ++c) acc += emb[(size_t)row[c] * Dn + d];
  x[(size_t)bs * Dn + d] = acc;
  xbf[(size_t)bs * Dn + d] = f2bf(acc);
}

// ---------------------------------------------------------------------------
// bf16 MFMA GEMM: C[M,N] = A[M,K=256] @ B[N,K=256]^T + bias[N], f32 out.
// M%64==0, N%64==0. 64x64 tile, 4 waves (2x2), each wave 32x32 via 2x2 frags.
__global__ __launch_bounds__(256) void k_gemm_bf16(const ushort* __restrict__ A,
    const ushort* __restrict__ Bm, const float* __restrict__ bias,
    float* __restrict__ C, int M, int N) {
  __shared__ ushort As[64 * 40];  // stride 40 elems (80B): 2-way max on frag reads
  __shared__ ushort Bs[64 * 40];
  const int tid = threadIdx.x;
  const int m0 = blockIdx.x * 64, n0 = blockIdx.y * 64;
  const int wave = tid >> 6, lane = tid & 63;
  const int wr = wave >> 1, wc = wave & 1;
  const int lrow = tid >> 2, lseg = (tid & 3) * 8;   // staging map
  const int r16 = lane & 15, kg = lane >> 4;         // fragment map
  f32x4 acc[2][2] = {};
  for (int k0 = 0; k0 < 256; k0 += 32) {
    *(uint4*)&As[lrow * 40 + lseg] =
        *(const uint4*)&A[(size_t)(m0 + lrow) * 256 + k0 + lseg];
    *(uint4*)&Bs[lrow * 40 + lseg] =
        *(const uint4*)&Bm[(size_t)(n0 + lrow) * 256 + k0 + lseg];
    __syncthreads();
    bf16x8 a0 = *(const bf16x8*)&As[(wr * 32 + r16) * 40 + kg * 8];
    bf16x8 a1 = *(const bf16x8*)&As[(wr * 32 + 16 + r16) * 40 + kg * 8];
    bf16x8 b0 = *(const bf16x8*)&Bs[(wc * 32 + r16) * 40 + kg * 8];
    bf16x8 b1 = *(const bf16x8*)&Bs[(wc * 32 + 16 + r16) * 40 + kg * 8];
    acc[0][0] = __builtin_amdgcn_mfma_f32_16x16x32_bf16(a0, b0, acc[0][0], 0, 0, 0);
    acc[0][1] = __builtin_amdgcn_mfma_f32_16x16x32_bf16(a0, b1, acc[0][1], 0, 0, 0);
    acc[1][0] = __builtin_amdgcn_mfma_f32_16x16x32_bf16(a1, b0, acc[1][0], 0, 0, 0);
    acc[1][1] = __builtin_amdgcn_mfma_f32_16x16x32_bf16(a1, b1, acc[1][1], 0, 0, 0);
    __syncthreads();
  }
#pragma unroll
  for (int mi = 0; mi < 2; ++mi)
#pragma unroll
    for (int ni = 0; ni < 2; ++ni)
#pragma unroll
      for (int r = 0; r < 4; ++r) {
        int gr = m0 + wr * 32 + mi * 16 + kg * 4 + r;
        int gc = n0 + wc * 32 + ni * 16 + r16;
        C[(size_t)gr * N + gc] = acc[mi][ni][r] + bias[gc];
      }
}

// ---------------------------------------------------------------------------
// GRU, register-resident f16 Whh, full-K per thread. One block per batch.
// 256 threads: thread d owns gate rows {d, D+d, 2D+d} over ALL K=256
// (3 x 128 u32 = 384 VGPRs; launch_bounds(256,1) -> 512-reg budget).
// No cross-thread reduce. h reads are same-address LDS broadcasts.
// One barrier per step (double-buffered h).
__global__ __launch_bounds__(256, 1) void k_gru_reg3(const float* __restrict__ xp,
    const uint* __restrict__ Wh, const float* __restrict__ bhh,
    float* __restrict__ out, ushort* __restrict__ out_bf) {
  const int b = blockIdx.x;
  const int d = threadIdx.x;
  __shared__ uint h2s[2][128];  // h[256] as f16 pairs, double-buffered

  uint wr_[128], wz_[128], wn_[128];
#pragma unroll
  for (int i = 0; i < 128; i += 4) {
    uint4 v;
    v = *reinterpret_cast<const uint4*>(Wh + (size_t)d * 128 + i);
    wr_[i] = v.x; wr_[i + 1] = v.y; wr_[i + 2] = v.z; wr_[i + 3] = v.w;
    v = *reinterpret_cast<const uint4*>(Wh + (size_t)(256 + d) * 128 + i);
    wz_[i] = v.x; wz_[i + 1] = v.y; wz_[i + 2] = v.z; wz_[i + 3] = v.w;
    v = *reinterpret_cast<const uint4*>(Wh + (size_t)(512 + d) * 128 + i);
    wn_[i] = v.x; wn_[i + 1] = v.y; wn_[i + 2] = v.z; wn_[i + 3] = v.w;
  }
  const float* xpb = xp + (size_t)b * Sn * G3;
  const float b_r = bhh[d], b_z = bhh[256 + d], b_n = bhh[512 + d];
  float x_r = xpb[d], x_z = xpb[256 + d], x_n = xpb[512 + d];
  float h_old = 0.f;
  if (d < 128) h2s[0][d] = 0u;
  __syncthreads();

  for (int t = 0; t < Sn; ++t) {
    const int cur = t & 1;
    float ar = 0.f, az = 0.f, an = 0.f;
#pragma unroll
    for (int c = 0; c < 16; ++c) {  // 8 u32 of h per chunk (broadcast reads)
      uint4 v0 = *reinterpret_cast<const uint4*>(&h2s[cur][8 * c]);
      uint4 v1 = *reinterpret_cast<const uint4*>(&h2s[cur][8 * c + 4]);
      uint hh[8] = {v0.x, v0.y, v0.z, v0.w, v1.x, v1.y, v1.z, v1.w};
#pragma unroll
      for (int i = 0; i < 8; ++i) {
        h2_t hv = as_h2(hh[i]);
        ar = __builtin_amdgcn_fdot2(as_h2(wr_[8 * c + i]), hv, ar, false);
        az = __builtin_amdgcn_fdot2(as_h2(wz_[8 * c + i]), hv, az, false);
        an = __builtin_amdgcn_fdot2(as_h2(wn_[8 * c + i]), hv, an, false);
      }
    }
    float rv = 1.f / (1.f + __expf(-(x_r + ar + b_r)));
    float zv = 1.f / (1.f + __expf(-(x_z + az + b_z)));
    float nv = tanhf(x_n + rv * (an + b_n));
    float h = (1.f - zv) * nv + zv * h_old;
    h_old = h;
    const size_t oi = ((size_t)b * Sn + t) * Dn + d;
    out[oi] = h;
    if (out_bf) out_bf[oi] = f2bf(h);
    if (t + 1 < Sn) {
      const float* xr = xpb + (size_t)(t + 1) * G3;
      x_r = xr[d]; x_z = xr[256 + d]; x_n = xr[512 + d];
    }
    float hp2 = __shfl_xor(h, 1);
    if ((d & 1) == 0) h2s[cur ^ 1][d >> 1] = as_u32(__builtin_amdgcn_cvt_pkrtz(h, hp2));
    __syncthreads();
  }
}

// ---------------------------------------------------------------------------
// Parallel location-attention + blend (unchanged from round 6)
__global__ __launch_bounds__(256) void k_attn_par(const float* __restrict__ x,
    const float* __restrict__ wprev, const float* __restrict__ w1W,
    const float* __restrict__ w1b, const float* __restrict__ w2W,
    const float* __restrict__ w2b, float* __restrict__ aligned) {
  extern __shared__ float sm[];
  float* w1s = sm;                  // 64 x 513
  float* ek  = w1s + 64 * 513;
  float* wp  = ek + 256;
  float* eks = wp + 256;
  float* t1  = eks + 64;
  float* a01 = t1 + 64;
  const int b = blockIdx.x, cy = blockIdx.y, tid = threadIdx.x;
  for (int idx = tid; idx < 64 * 512; idx += 256) {
    int f = idx >> 9, c = idx & 511;
    w1s[f * 513 + c] = w1W[idx];
  }
  ek[tid] = x[(size_t)b * Sn * Dn + tid];
  __syncthreads();
  const int f = tid >> 2, kq = tid & 3;
  {
    float p = 0.f;
    const float* wr = w1s + f * 513;
#pragma unroll 8
    for (int j = 0; j < 64; ++j) {
      int k = 64 * kq + ((j + 16 * kq) & 63);
      p += ek[k] * wr[k];
    }
    p += __shfl_xor(p, 1);
    p += __shfl_xor(p, 2);
    if (kq == 0) eks[f] = p + w1b[f];
  }
  if (cy == 0) aligned[(size_t)b * Sn * Dn + tid] = ek[tid];
  __syncthreads();
  const int s0 = 1 + cy * 29;
  const int s1 = (s0 + 29 < Sn) ? s0 + 29 : Sn;
  for (int s = s0; s < s1; ++s) {
    wp[tid] = wprev[((size_t)b * Sn + (s - 1)) * Dn + tid];
    __syncthreads();
    float p = 0.f;
    const float* wr = w1s + f * 513 + 256;
#pragma unroll 8
    for (int j = 0; j < 64; ++j) {
      int k = 64 * kq + ((j + 16 * kq) & 63);
      p += wp[k] * wr[k];
    }
    p += __shfl_xor(p, 1);
    p += __shfl_xor(p, 2);
    if (kq == 0) t1[f] = tanhf(eks[f] + p);
    __syncthreads();
    if (tid == 0) {
      float l0 = w2b[0], l1 = w2b[1];
#pragma unroll
      for (int j = 0; j < 64; ++j) { l0 += t1[j] * w2W[j]; l1 += t1[j] * w2W[64 + j]; }
      float m = fmaxf(l0, l1);
      float e0 = __expf(l0 - m), e1 = __expf(l1 - m);
      float inv = 1.f / (e0 + e1);
      a01[0] = e0 * inv; a01[1] = e1 * inv;
    }
    __syncthreads();
    aligned[((size_t)b * Sn + s) * Dn + tid] = ek[tid] * a01[0] + wp[tid] * a01[1];
    __syncthreads();
  }
}

// ---------------------------------------------------------------------------
__global__ __launch_bounds__(256) void k_cumsetup(const float* __restrict__ betas,
    const int* __restrict__ difft, const float* __restrict__ tscale,
    float* __restrict__ sa, float* __restrict__ sb, float* __restrict__ tsv) {
  __shared__ float bl[Tn];
  const int tid = threadIdx.x;
  for (int i = tid; i < Tn; i += 256) bl[i] = betas[i];
  __syncthreads();
  if (tid == 0) {
    float p = 1.f;
    for (int t = 0; t < Tn; ++t) { p *= (1.f - bl[t]); bl[t] = p; }
  }
  __syncthreads();
  if (tid < Bn) {
    int tb = difft[tid];
    float a = bl[tb];
    sa[tid] = sqrtf(a);
    sb[tid] = sqrtf(1.f - a);
    tsv[tid] = tscale[tb];
  }
}

// ---------------------------------------------------------------------------
__global__ __launch_bounds__(256) void k_noisy(const float* __restrict__ aligned,
    const float* __restrict__ noise, const float* __restrict__ sa,
    const float* __restrict__ sb, float* __restrict__ xn) {
  const size_t NT = (size_t)Bn * Sn * Dn;
  const size_t stride = (size_t)gridDim.x * blockDim.x;
  for (size_t i = (size_t)blockIdx.x * blockDim.x + threadIdx.x; i < NT; i += stride) {
    int b = (int)(i / (Sn * Dn));
    xn[i] = aligned[i] * sa[b] + noise[i] * sb[b];
  }
}

// ---------------------------------------------------------------------------
// pn[b,c,d] = ts[b]*sum_s Wd[c,s]*xn[b,s,d];  genx_bf = bf16(aligned+noise-pn)
__global__ __launch_bounds__(256) void k_diff(const float* __restrict__ Wd,
    const float* __restrict__ Xn, const float* __restrict__ tsv,
    const float* __restrict__ aligned, const float* __restrict__ noise,
    float* __restrict__ pn, ushort* __restrict__ genx_bf) {
  const int bz = blockIdx.z;
  const float* Bm = Xn + (size_t)bz * Sn * Dn;
  __shared__ float As[16][65];
  __shared__ float Bs[16][65];
  const int m0 = blockIdx.x * 64, n0 = blockIdx.y * 64;
  const int tid = threadIdx.x;
  const int lk = tid & 15, lm = tid >> 4;
  const int ln = tid & 63, lq = tid >> 6;
  const int tx = tid & 15, ty = tid >> 4;
  float acc[4][4] = {};
  for (int k0 = 0; k0 < Sn; k0 += 16) {
#pragma unroll
    for (int i = 0; i < 4; ++i) {
      int m = lm + i * 16;
      As[lk][m] = (m0 + m < Sn && k0 + lk < Sn) ? Wd[(size_t)(m0 + m) * Sn + k0 + lk] : 0.f;
    }
#pragma unroll
    for (int i = 0; i < 4; ++i) {
      int k = lq + i * 4;
      Bs[k][ln] = (k0 + k < Sn) ? Bm[(size_t)(k0 + k) * Dn + n0 + ln] : 0.f;
    }
    __syncthreads();
#pragma unroll
    for (int k = 0; k < 16; ++k) {
      float a[4], bb[4];
#pragma unroll
      for (int i = 0; i < 4; ++i) a[i] = As[k][ty * 4 + i];
#pragma unroll
      for (int j = 0; j < 4; ++j) bb[j] = Bs[k][tx * 4 + j];
#pragma unroll
      for (int i = 0; i < 4; ++i)
#pragma unroll
        for (int j = 0; j < 4; ++j) acc[i][j] += a[i] * bb[j];
    }
    __syncthreads();
  }
  const float ts = tsv[bz];
#pragma unroll
  for (int i = 0; i < 4; ++i) {
    int c = m0 + ty * 4 + i;
    if (c >= Sn) continue;
#pragma unroll
    for (int j = 0; j < 4; ++j) {
      int dd = n0 + tx * 4 + j;
      size_t idx = ((size_t)bz * Sn + c) * Dn + dd;
      float val = acc[i][j] * ts;
      pn[idx] = val;
      genx_bf[idx] = f2bf(aligned[idx] + noise[idx] - val);
    }
  }
}

// ---------------------------------------------------------------------------
__global__ __launch_bounds__(256) void k_pool(const float* __restrict__ rnn,
    const float* __restrict__ wlW, const float* __restrict__ wlb,
    const float* __restrict__ outW, const float* __restrict__ outb,
    float* __restrict__ out2) {
  const int b = blockIdx.x, tid = threadIdx.x;
  __shared__ float wl[Dn], att[256], red[256], feat[Dn];
  wl[tid] = wlW[tid];
  __syncthreads();
  float wv = -1e30f;
  if (tid < Sn) {
    const float* r = rnn + ((size_t)b * Sn + tid) * Dn;
    float a = wlb[0];
    for (int k = 0; k < Dn; ++k) a += r[k] * wl[k];
    wv = a;
  }
  red[tid] = wv;
  __syncthreads();
  for (int off = 128; off > 0; off >>= 1) {
    if (tid < off) red[tid] = fmaxf(red[tid], red[tid + off]);
    __syncthreads();
  }
  const float m = red[0];
  __syncthreads();
  float e = (tid < Sn) ? __expf(wv - m) : 0.f;
  red[tid] = e;
  __syncthreads();
  for (int off = 128; off > 0; off >>= 1) {
    if (tid < off) red[tid] += red[tid + off];
    __syncthreads();
  }
  const float inv = 1.f / red[0];
  att[tid] = e * inv;
  __syncthreads();
  const float* rb = rnn + (size_t)b * Sn * Dn;
  float a = 0.f;
  for (int s = 0; s < Sn; ++s) a += rb[(size_t)s * Dn + tid] * att[s];
  feat[tid] = a;
  __syncthreads();
  if (tid < 2) {
    float acc = outb[tid];
    for (int k = 0; k < Dn; ++k) acc += feat[k] * outW[tid * Dn + k];
    out2[b * 2 + tid] = acc;
  }
}

// ---------------------------------------------------------------------------
extern "C" void kernel_launch(void* const* d_in, const int* in_sizes, int n_in,
                              void* d_out, int out_size, void* d_ws, size_t ws_size,
                              hipStream_t stream) {
  const int*   seqs   = (const int*)  d_in[0];
  const int*   difft  = (const int*)  d_in[5];
  const float* emb    = (const float*)d_in[6];
  const float* Wih    = (const float*)d_in[7];
  const float* Whh    = (const float*)d_in[8];
  const float* bih    = (const float*)d_in[9];
  const float* bhh    = (const float*)d_in[10];
  const float* whkW   = (const float*)d_in[11];
  const float* whkb   = (const float*)d_in[12];
  const float* w1W    = (const float*)d_in[13];
  const float* w1b    = (const float*)d_in[14];
  const float* w2W    = (const float*)d_in[15];
  const float* w2b    = (const float*)d_in[16];
  const float* wlW    = (const float*)d_in[17];
  const float* wlb    = (const float*)d_in[18];
  const float* outW   = (const float*)d_in[19];
  const float* outb   = (const float*)d_in[20];
  const float* betas  = (const float*)d_in[21];
  const float* Wd     = (const float*)d_in[22];
  const float* tscale = (const float*)d_in[23];
  const float* noise  = (const float*)d_in[24];

  float* ws = (float*)d_ws;
  const size_t NX  = (size_t)Bn * Sn * Dn;  // 3,276,800
  const size_t NXP = (size_t)Bn * Sn * G3;  // 9,830,400
  // f32 regions
  float* x       = ws;                  // [0, NX)           live to step 5
  float* xp      = ws + NX;             // [NX, NX+NXP)
  float* xnoisy  = xp;                  //   aliases xp[0,NX)     (steps 7-8)
  float* aligned = xp + NX;             //   aliases xp[NX,2NX)   (steps 5-8)
  float* rnn     = ws + NX + NXP;       // live to step 11
  float* wprev   = ws + 2 * NX + NXP;   // w_prev (4-5) -> genx_bf (8-9) -> gen_rnn (10-11)
  ushort* x_bf   = (ushort*)wprev;      //   alias: used step 2, dead before step 4
  ushort* genx_bf= (ushort*)wprev;      //   alias: written 8, read 9, dead before 10
  // tail
  float* sa      = ws + 3 * NX + NXP;
  float* sb      = sa + 64;
  float* tsv     = sb + 64;
  uint*  Wf16    = (uint*)(tsv + 64);         // 98304 u32
  ushort* rnn_bf = (ushort*)(Wf16 + 98304);   // NX ushorts (steps 3-4)
  ushort* Wih_bf = rnn_bf + NX;               // 196608
  ushort* whk_bf = Wih_bf + 196608;           // 65536

  float* out       = (float*)d_out;
  float* pred      = out;
  float* gpred     = out + 128;
  float* pn        = out + 256;
  float* out_noise = out + 256 + NX;

  const int ATTN_SMEM = (64 * 513 + 256 + 256 + 64 + 64 + 2) * 4;

  // 0. weight conversions
  k_w2f16<<<dim3(384), dim3(256), 0, stream>>>(Whh, Wf16, 98304);
  k_w2bf<<<dim3(768), dim3(256), 0, stream>>>(Wih, Wih_bf, 196608);
  k_w2bf<<<dim3(256), dim3(256), 0, stream>>>(whkW, whk_bf, 65536);
  // 1. embedding sum (f32 + bf16)
  k_embed_sum<<<dim3(Bn * Sn), dim3(Dn), 0, stream>>>(seqs, emb, x, x_bf);
  // 2. xp = x @ Wih^T + bih   (MFMA bf16)
  k_gemm_bf16<<<dim3(200, 12), dim3(256), 0, stream>>>(x_bf, Wih_bf, bih, xp, Bn * Sn, G3);
  // 3. rnn = GRU(xp)
  k_gru_reg3<<<dim3(Bn), dim3(256), 0, stream>>>(xp, Wf16, bhh, rnn, rnn_bf);
  // 4. w_prev = rnn @ whk^T + b  (MFMA bf16)
  k_gemm_bf16<<<dim3(200, 4), dim3(256), 0, stream>>>(rnn_bf, whk_bf, whkb, wprev, Bn * Sn, Dn);
  // 5. attention + blend -> aligned
  k_attn_par<<<dim3(Bn, 7), dim3(256), ATTN_SMEM, stream>>>(x, wprev, w1W, w1b, w2W, w2b, aligned);
  // 6. diffusion scalars
  k_cumsetup<<<dim3(1), dim3(256), 0, stream>>>(betas, difft, tscale, sa, sb, tsv);
  // 7. x_noisy (into dead xp[0,NX))
  k_noisy<<<dim3(2048), dim3(256), 0, stream>>>(aligned, noise, sa, sb, xnoisy);
  // 8. pn (-> d_out) and genx_bf (into wprev region, now dead)
  k_diff<<<dim3(4, 4, Bn), dim3(256), 0, stream>>>(Wd, xnoisy, tsv, aligned, noise, pn, genx_bf);
  // 9. gen xp = gen_x @ Wih^T + bih  (MFMA bf16)
  k_gemm_bf16<<<dim3(200, 12), dim3(256), 0, stream>>>(genx_bf, Wih_bf, bih, xp, Bn * Sn, G3);
  // 10. gen_rnn = GRU (overwrites wprev region; genx_bf dead)
  k_gru_reg3<<<dim3(Bn), dim3(256), 0, stream>>>(xp, Wf16, bhh, wprev, (ushort*)nullptr);
  // 11. pools
  k_pool<<<dim3(Bn), dim3(256), 0, stream>>>(rnn, wlW, wlb, outW, outb, pred);
  k_pool<<<dim3(Bn), dim3(256), 0, stream>>>(wprev, wlW, wlb, outW, outb, gpred);
  // 12. pass through normal_noise
  (void)hipMemcpyAsync(out_noise, noise, NX * sizeof(float), hipMemcpyDeviceToDevice, stream);
}

// Round 9
// 1018.283 us; speedup vs baseline: 1.4602x; 1.4602x over previous
//
#include <hip/hip_runtime.h>
#include <math.h>

// Problem constants
constexpr int Bn = 64, Sn = 200, Cn = 32, Dn = 256, Vn = 10000, Tn = 1000;
constexpr int G3 = 3 * Dn; // 768
constexpr int KP = 224;    // padded diffusion K (200 -> 224, multiple of 32)

typedef __fp16 h2_t __attribute__((ext_vector_type(2)));
typedef short bf16x8 __attribute__((ext_vector_type(8)));
typedef float f32x4 __attribute__((ext_vector_type(4)));

static __device__ __forceinline__ h2_t as_h2(uint v) {
  union { uint u; h2_t h; } c; c.u = v; return c.h;
}
static __device__ __forceinline__ uint as_u32(h2_t h) {
  union { h2_t h; uint u; } c; c.h = h; return c.u;
}
static __device__ __forceinline__ ushort f2bf(float f) {  // RNE f32->bf16
  uint u = __float_as_uint(f);
  u += 0x7FFFu + ((u >> 16) & 1u);
  return (ushort)(u >> 16);
}

// ---------------------------------------------------------------------------
__global__ __launch_bounds__(256) void k_w2f16(const float* __restrict__ w,
    uint* __restrict__ o, int npairs) {
  int i = blockIdx.x * 256 + threadIdx.x;
  if (i < npairs) {
    h2_t pk = __builtin_amdgcn_cvt_pkrtz(w[2 * i], w[2 * i + 1]);
    o[i] = as_u32(pk);
  }
}

__global__ __launch_bounds__(256) void k_w2bf(const float* __restrict__ w,
    ushort* __restrict__ o, int n) {
  int i = blockIdx.x * 256 + threadIdx.x;
  if (i < n) o[i] = f2bf(w[i]);
}

// Wd [200][200] f32 -> bf16 [200][224] zero-padded cols
__global__ __launch_bounds__(256) void k_wd2bf(const float* __restrict__ w,
    ushort* __restrict__ o) {
  int i = blockIdx.x * 256 + threadIdx.x;
  if (i < Sn * KP) {
    int r = i / KP, c = i % KP;
    o[i] = (c < Sn) ? f2bf(w[r * Sn + c]) : (ushort)0;
  }
}

// ---------------------------------------------------------------------------
__global__ __launch_bounds__(256) void k_embed_sum(const int* __restrict__ seqs,
    const float* __restrict__ emb, float* __restrict__ x, ushort* __restrict__ xbf) {
  const int bs = blockIdx.x;
  const int d = threadIdx.x;
  const int* row = seqs + (size_t)bs * Cn;
  float acc = 0.f;
#pragma unroll
  for (int c = 0; c < Cn; ++c) acc += emb[(size_t)row[c] * Dn + d];
  x[(size_t)bs * Dn + d] = acc;
  xbf[(size_t)bs * Dn + d] = f2bf(acc);
}

// ---------------------------------------------------------------------------
// bf16 MFMA GEMM: C[M,N] = A[M,K=256] @ B[N,K=256]^T + bias[N], f32 out.
__global__ __launch_bounds__(256) void k_gemm_bf16(const ushort* __restrict__ A,
    const ushort* __restrict__ Bm, const float* __restrict__ bias,
    float* __restrict__ C, int M, int N) {
  __shared__ ushort As[64 * 40];
  __shared__ ushort Bs[64 * 40];
  const int tid = threadIdx.x;
  const int m0 = blockIdx.x * 64, n0 = blockIdx.y * 64;
  const int wave = tid >> 6, lane = tid & 63;
  const int wr = wave >> 1, wc = wave & 1;
  const int lrow = tid >> 2, lseg = (tid & 3) * 8;
  const int r16 = lane & 15, kg = lane >> 4;
  f32x4 acc[2][2] = {};
  for (int k0 = 0; k0 < 256; k0 += 32) {
    *(uint4*)&As[lrow * 40 + lseg] =
        *(const uint4*)&A[(size_t)(m0 + lrow) * 256 + k0 + lseg];
    *(uint4*)&Bs[lrow * 40 + lseg] =
        *(const uint4*)&Bm[(size_t)(n0 + lrow) * 256 + k0 + lseg];
    __syncthreads();
    bf16x8 a0 = *(const bf16x8*)&As[(wr * 32 + r16) * 40 + kg * 8];
    bf16x8 a1 = *(const bf16x8*)&As[(wr * 32 + 16 + r16) * 40 + kg * 8];
    bf16x8 b0 = *(const bf16x8*)&Bs[(wc * 32 + r16) * 40 + kg * 8];
    bf16x8 b1 = *(const bf16x8*)&Bs[(wc * 32 + 16 + r16) * 40 + kg * 8];
    acc[0][0] = __builtin_amdgcn_mfma_f32_16x16x32_bf16(a0, b0, acc[0][0], 0, 0, 0);
    acc[0][1] = __builtin_amdgcn_mfma_f32_16x16x32_bf16(a0, b1, acc[0][1], 0, 0, 0);
    acc[1][0] = __builtin_amdgcn_mfma_f32_16x16x32_bf16(a1, b0, acc[1][0], 0, 0, 0);
    acc[1][1] = __builtin_amdgcn_mfma_f32_16x16x32_bf16(a1, b1, acc[1][1], 0, 0, 0);
    __syncthreads();
  }
#pragma unroll
  for (int mi = 0; mi < 2; ++mi)
#pragma unroll
    for (int ni = 0; ni < 2; ++ni)
#pragma unroll
      for (int r = 0; r < 4; ++r) {
        int gr = m0 + wr * 32 + mi * 16 + kg * 4 + r;
        int gc = n0 + wc * 32 + ni * 16 + r16;
        C[(size_t)gr * N + gc] = acc[mi][ni][r] + bias[gc];
      }
}

// ---------------------------------------------------------------------------
// GRU, gate-split geometry: 768 threads, thread (g,d) owns one gate row
// (128 weight u32 in arch VGPRs, launch_bounds(768,3) -> 170-reg budget).
// red exchange via LDS (conflict-free); h reads broadcast; act on g==0 waves.
__global__ __launch_bounds__(768, 3) void k_gru_g(const float* __restrict__ xp,
    const uint* __restrict__ Wh, const float* __restrict__ bhh,
    float* __restrict__ out, ushort* __restrict__ out_bf) {
  const int b = blockIdx.x;
  const int tid = threadIdx.x;
  const int g = tid >> 8;
  const int d = tid & 255;
  __shared__ uint h2s[2][128];
  __shared__ float red[768];

  uint w_[128];
#pragma unroll
  for (int i = 0; i < 128; i += 4) {
    uint4 v = *reinterpret_cast<const uint4*>(Wh + (size_t)(g * 256 + d) * 128 + i);
    w_[i] = v.x; w_[i + 1] = v.y; w_[i + 2] = v.z; w_[i + 3] = v.w;
  }
  const float* xpb = xp + (size_t)b * Sn * G3;
  const float bias = bhh[g * 256 + d];
  float xv = (g == 2) ? 0.f : xpb[g * 256 + d];   // r/z fold x into red; n does not
  float xnv = (g == 0) ? xpb[512 + d] : 0.f;      // g0 tracks x_n separately
  float h_old = 0.f;
  if (tid < 128) h2s[0][tid] = 0u;
  __syncthreads();

  for (int t = 0; t < Sn; ++t) {
    const int cur = t & 1;
    float a0 = 0.f, a1 = 0.f;
#pragma unroll
    for (int c = 0; c < 8; ++c) {
      uint4 v0 = *reinterpret_cast<const uint4*>(&h2s[cur][8 * c]);
      uint4 v1 = *reinterpret_cast<const uint4*>(&h2s[cur][8 * c + 4]);
      uint hh[8] = {v0.x, v0.y, v0.z, v0.w, v1.x, v1.y, v1.z, v1.w};
#pragma unroll
      for (int i = 0; i < 8; ++i)
        a0 = __builtin_amdgcn_fdot2(as_h2(w_[8 * c + i]), as_h2(hh[i]), a0, false);
    }
#pragma unroll
    for (int c = 8; c < 16; ++c) {
      uint4 v0 = *reinterpret_cast<const uint4*>(&h2s[cur][8 * c]);
      uint4 v1 = *reinterpret_cast<const uint4*>(&h2s[cur][8 * c + 4]);
      uint hh[8] = {v0.x, v0.y, v0.z, v0.w, v1.x, v1.y, v1.z, v1.w};
#pragma unroll
      for (int i = 0; i < 8; ++i)
        a1 = __builtin_amdgcn_fdot2(as_h2(w_[8 * c + i]), as_h2(hh[i]), a1, false);
    }
    red[tid] = a0 + a1 + xv + bias;
    float xnv_c = xnv;
    if (t + 1 < Sn) {
      const float* xr = xpb + (size_t)(t + 1) * G3;
      if (g != 2) xv = xr[g * 256 + d];
      if (g == 0) xnv = xr[512 + d];
    }
    __syncthreads();
    if (g == 0) {
      float rv = 1.f / (1.f + __expf(-red[d]));
      float zv = 1.f / (1.f + __expf(-red[256 + d]));
      float nv = tanhf(xnv_c + rv * red[512 + d]);
      float h = (1.f - zv) * nv + zv * h_old;
      h_old = h;
      const size_t oi = ((size_t)b * Sn + t) * Dn + d;
      out[oi] = h;
      if (out_bf) out_bf[oi] = f2bf(h);
      float hp2 = __shfl_xor(h, 1);
      if ((d & 1) == 0) h2s[cur ^ 1][d >> 1] = as_u32(__builtin_amdgcn_cvt_pkrtz(h, hp2));
    }
    __syncthreads();
  }
}

// ---------------------------------------------------------------------------
__global__ __launch_bounds__(256) void k_attn_par(const float* __restrict__ x,
    const float* __restrict__ wprev, const float* __restrict__ w1W,
    const float* __restrict__ w1b, const float* __restrict__ w2W,
    const float* __restrict__ w2b, float* __restrict__ aligned) {
  extern __shared__ float sm[];
  float* w1s = sm;
  float* ek  = w1s + 64 * 513;
  float* wp  = ek + 256;
  float* eks = wp + 256;
  float* t1  = eks + 64;
  float* a01 = t1 + 64;
  const int b = blockIdx.x, cy = blockIdx.y, tid = threadIdx.x;
  for (int idx = tid; idx < 64 * 512; idx += 256) {
    int f = idx >> 9, c = idx & 511;
    w1s[f * 513 + c] = w1W[idx];
  }
  ek[tid] = x[(size_t)b * Sn * Dn + tid];
  __syncthreads();
  const int f = tid >> 2, kq = tid & 3;
  {
    float p = 0.f;
    const float* wr = w1s + f * 513;
#pragma unroll 8
    for (int j = 0; j < 64; ++j) {
      int k = 64 * kq + ((j + 16 * kq) & 63);
      p += ek[k] * wr[k];
    }
    p += __shfl_xor(p, 1);
    p += __shfl_xor(p, 2);
    if (kq == 0) eks[f] = p + w1b[f];
  }
  if (cy == 0) aligned[(size_t)b * Sn * Dn + tid] = ek[tid];
  __syncthreads();
  const int s0 = 1 + cy * 29;
  const int s1 = (s0 + 29 < Sn) ? s0 + 29 : Sn;
  for (int s = s0; s < s1; ++s) {
    wp[tid] = wprev[((size_t)b * Sn + (s - 1)) * Dn + tid];
    __syncthreads();
    float p = 0.f;
    const float* wr = w1s + f * 513 + 256;
#pragma unroll 8
    for (int j = 0; j < 64; ++j) {
      int k = 64 * kq + ((j + 16 * kq) & 63);
      p += wp[k] * wr[k];
    }
    p += __shfl_xor(p, 1);
    p += __shfl_xor(p, 2);
    if (kq == 0) t1[f] = tanhf(eks[f] + p);
    __syncthreads();
    if (tid == 0) {
      float l0 = w2b[0], l1 = w2b[1];
#pragma unroll
      for (int j = 0; j < 64; ++j) { l0 += t1[j] * w2W[j]; l1 += t1[j] * w2W[64 + j]; }
      float m = fmaxf(l0, l1);
      float e0 = __expf(l0 - m), e1 = __expf(l1 - m);
      float inv = 1.f / (e0 + e1);
      a01[0] = e0 * inv; a01[1] = e1 * inv;
    }
    __syncthreads();
    aligned[((size_t)b * Sn + s) * Dn + tid] = ek[tid] * a01[0] + wp[tid] * a01[1];
    __syncthreads();
  }
}

// ---------------------------------------------------------------------------
__global__ __launch_bounds__(256) void k_cumsetup(const float* __restrict__ betas,
    const int* __restrict__ difft, const float* __restrict__ tscale,
    float* __restrict__ sa, float* __restrict__ sb, float* __restrict__ tsv) {
  __shared__ float bl[Tn];
  const int tid = threadIdx.x;
  for (int i = tid; i < Tn; i += 256) bl[i] = betas[i];
  __syncthreads();
  if (tid == 0) {
    float p = 1.f;
    for (int t = 0; t < Tn; ++t) { p *= (1.f - bl[t]); bl[t] = p; }
  }
  __syncthreads();
  if (tid < Bn) {
    int tb = difft[tid];
    float a = bl[tb];
    sa[tid] = sqrtf(a);
    sb[tid] = sqrtf(1.f - a);
    tsv[tid] = tscale[tb];
  }
}

// ---------------------------------------------------------------------------
// x_noisy, transposed bf16: xnT[b][d][s_pad], zero-padded s in [200,224).
__global__ __launch_bounds__(256) void k_noisy_t(const float* __restrict__ aligned,
    const float* __restrict__ noise, const float* __restrict__ sa,
    const float* __restrict__ sb, ushort* __restrict__ xnT) {
  __shared__ float T[256][33];
  const int b = blockIdx.x, sy = blockIdx.y;
  const int tid = threadIdx.x;
  const float A = sa[b], Bc = sb[b];
#pragma unroll 4
  for (int i = 0; i < 32; ++i) {
    int s = 32 * sy + i;
    float v = 0.f;
    if (s < Sn) {
      size_t idx = ((size_t)b * Sn + s) * Dn + tid;
      v = aligned[idx] * A + noise[idx] * Bc;
    }
    T[tid][i] = v;
  }
  __syncthreads();
  const int sl = tid & 31, dq = tid >> 5;
#pragma unroll 4
  for (int dd = 0; dd < 32; ++dd) {
    int d = dq * 32 + dd;
    xnT[((size_t)b * Dn + d) * KP + 32 * sy + sl] = f2bf(T[d][sl]);
  }
}

// ---------------------------------------------------------------------------
// Batched diffusion GEMM (MFMA): pn[b,c,d] = ts[b]*sum_s Wd[c,s]*xn[b,s,d];
// epilogue writes pn (f32) and genx_bf = bf16(aligned + noise - pn).
__global__ __launch_bounds__(256) void k_diff_mfma(const ushort* __restrict__ Wd_bf,
    const ushort* __restrict__ xnT, const float* __restrict__ tsv,
    const float* __restrict__ aligned, const float* __restrict__ noise,
    float* __restrict__ pn, ushort* __restrict__ genx_bf) {
  __shared__ ushort As[64 * 40];
  __shared__ ushort Bs[64 * 40];
  const int bz = blockIdx.z;
  const int tid = threadIdx.x;
  const int m0 = blockIdx.x * 64, n0 = blockIdx.y * 64;
  const int wave = tid >> 6, lane = tid & 63;
  const int wr = wave >> 1, wc = wave & 1;
  const int lrow = tid >> 2, lseg = (tid & 3) * 8;
  const int r16 = lane & 15, kg = lane >> 4;
  const ushort* Bb = xnT + (size_t)bz * Dn * KP;
  f32x4 acc[2][2] = {};
  for (int k0 = 0; k0 < KP; k0 += 32) {
    uint4 av = {0u, 0u, 0u, 0u};
    if (m0 + lrow < Sn)
      av = *(const uint4*)&Wd_bf[(size_t)(m0 + lrow) * KP + k0 + lseg];
    *(uint4*)&As[lrow * 40 + lseg] = av;
    *(uint4*)&Bs[lrow * 40 + lseg] =
        *(const uint4*)&Bb[(size_t)(n0 + lrow) * KP + k0 + lseg];
    __syncthreads();
    bf16x8 a0 = *(const bf16x8*)&As[(wr * 32 + r16) * 40 + kg * 8];
    bf16x8 a1 = *(const bf16x8*)&As[(wr * 32 + 16 + r16) * 40 + kg * 8];
    bf16x8 b0 = *(const bf16x8*)&Bs[(wc * 32 + r16) * 40 + kg * 8];
    bf16x8 b1 = *(const bf16x8*)&Bs[(wc * 32 + 16 + r16) * 40 + kg * 8];
    acc[0][0] = __builtin_amdgcn_mfma_f32_16x16x32_bf16(a0, b0, acc[0][0], 0, 0, 0);
    acc[0][1] = __builtin_amdgcn_mfma_f32_16x16x32_bf16(a0, b1, acc[0][1], 0, 0, 0);
    acc[1][0] = __builtin_amdgcn_mfma_f32_16x16x32_bf16(a1, b0, acc[1][0], 0, 0, 0);
    acc[1][1] = __builtin_amdgcn_mfma_f32_16x16x32_bf16(a1, b1, acc[1][1], 0, 0, 0);
    __syncthreads();
  }
  const float ts = tsv[bz];
#pragma unroll
  for (int mi = 0; mi < 2; ++mi)
#pragma unroll
    for (int ni = 0; ni < 2; ++ni)
#pragma unroll
      for (int r = 0; r < 4; ++r) {
        int gr = m0 + wr * 32 + mi * 16 + kg * 4 + r;
        int gc = n0 + wc * 32 + ni * 16 + r16;
        if (gr < Sn) {
          size_t idx = ((size_t)bz * Sn + gr) * Dn + gc;
          float val = acc[mi][ni][r] * ts;
          pn[idx] = val;
          genx_bf[idx] = f2bf(aligned[idx] + noise[idx] - val);
        }
      }
}

// ---------------------------------------------------------------------------
__global__ __launch_bounds__(256) void k_pool(const float* __restrict__ rnn,
    const float* __restrict__ wlW, const float* __restrict__ wlb,
    const float* __restrict__ outW, const float* __restrict__ outb,
    float* __restrict__ out2) {
  const int b = blockIdx.x, tid = threadIdx.x;
  __shared__ float wl[Dn], att[256], red[256], feat[Dn];
  wl[tid] = wlW[tid];
  __syncthreads();
  float wv = -1e30f;
  if (tid < Sn) {
    const float* r = rnn + ((size_t)b * Sn + tid) * Dn;
    float a = wlb[0];
    for (int k = 0; k < Dn; ++k) a += r[k] * wl[k];
    wv = a;
  }
  red[tid] = wv;
  __syncthreads();
  for (int off = 128; off > 0; off >>= 1) {
    if (tid < off) red[tid] = fmaxf(red[tid], red[tid + off]);
    __syncthreads();
  }
  const float m = red[0];
  __syncthreads();
  float e = (tid < Sn) ? __expf(wv - m) : 0.f;
  red[tid] = e;
  __syncthreads();
  for (int off = 128; off > 0; off >>= 1) {
    if (tid < off) red[tid] += red[tid + off];
    __syncthreads();
  }
  const float inv = 1.f / red[0];
  att[tid] = e * inv;
  __syncthreads();
  const float* rb = rnn + (size_t)b * Sn * Dn;
  float a = 0.f;
  for (int s = 0; s < Sn; ++s) a += rb[(size_t)s * Dn + tid] * att[s];
  feat[tid] = a;
  __syncthreads();
  if (tid < 2) {
    float acc = outb[tid];
    for (int k = 0; k < Dn; ++k) acc += feat[k] * outW[tid * Dn + k];
    out2[b * 2 + tid] = acc;
  }
}

// ---------------------------------------------------------------------------
extern "C" void kernel_launch(void* const* d_in, const int* in_sizes, int n_in,
                              void* d_out, int out_size, void* d_ws, size_t ws_size,
                              hipStream_t stream) {
  const int*   seqs   = (const int*)  d_in[0];
  const int*   difft  = (const int*)  d_in[5];
  const float* emb    = (const float*)d_in[6];
  const float* Wih    = (const float*)d_in[7];
  const float* Whh    = (const float*)d_in[8];
  const float* bih    = (const float*)d_in[9];
  const float* bhh    = (const float*)d_in[10];
  const float* whkW   = (const float*)d_in[11];
  const float* whkb   = (const float*)d_in[12];
  const float* w1W    = (const float*)d_in[13];
  const float* w1b    = (const float*)d_in[14];
  const float* w2W    = (const float*)d_in[15];
  const float* w2b    = (const float*)d_in[16];
  const float* wlW    = (const float*)d_in[17];
  const float* wlb    = (const float*)d_in[18];
  const float* outW   = (const float*)d_in[19];
  const float* outb   = (const float*)d_in[20];
  const float* betas  = (const float*)d_in[21];
  const float* Wd     = (const float*)d_in[22];
  const float* tscale = (const float*)d_in[23];
  const float* noise  = (const float*)d_in[24];

  float* ws = (float*)d_ws;
  const size_t NX  = (size_t)Bn * Sn * Dn;  // 3,276,800
  const size_t NXP = (size_t)Bn * Sn * G3;  // 9,830,400
  float* x       = ws;                  // live to step 5
  float* xp      = ws + NX;
  ushort* xnT    = (ushort*)xp;         // alias: written 7, read 8, dead at 9
  float* aligned = xp + NX;             // alias: written 5, read 7-8, dead at 9
  float* rnn     = ws + NX + NXP;
  float* wprev   = ws + 2 * NX + NXP;   // w_prev -> gen_rnn
  ushort* x_bf   = (ushort*)wprev;      // steps 1-2
  ushort* genx_bf= (ushort*)wprev;      // steps 8-9
  float* sa      = ws + 3 * NX + NXP;
  float* sb      = sa + 64;
  float* tsv     = sb + 64;
  uint*  Wf16    = (uint*)(tsv + 64);          // 98304
  ushort* rnn_bf = (ushort*)(Wf16 + 98304);    // NX
  ushort* Wih_bf = rnn_bf + NX;                // 196608
  ushort* whk_bf = Wih_bf + 196608;            // 65536
  ushort* Wd_bf  = whk_bf + 65536;             // 44800

  float* out       = (float*)d_out;
  float* pred      = out;
  float* gpred     = out + 128;
  float* pn        = out + 256;
  float* out_noise = out + 256 + NX;

  const int ATTN_SMEM = (64 * 513 + 256 + 256 + 64 + 64 + 2) * 4;

  k_w2f16<<<dim3(384), dim3(256), 0, stream>>>(Whh, Wf16, 98304);
  k_w2bf<<<dim3(768), dim3(256), 0, stream>>>(Wih, Wih_bf, 196608);
  k_w2bf<<<dim3(256), dim3(256), 0, stream>>>(whkW, whk_bf, 65536);
  k_wd2bf<<<dim3(175), dim3(256), 0, stream>>>(Wd, Wd_bf);
  k_embed_sum<<<dim3(Bn * Sn), dim3(Dn), 0, stream>>>(seqs, emb, x, x_bf);
  k_gemm_bf16<<<dim3(200, 12), dim3(256), 0, stream>>>(x_bf, Wih_bf, bih, xp, Bn * Sn, G3);
  k_gru_g<<<dim3(Bn), dim3(768), 0, stream>>>(xp, Wf16, bhh, rnn, rnn_bf);
  k_gemm_bf16<<<dim3(200, 4), dim3(256), 0, stream>>>(rnn_bf, whk_bf, whkb, wprev, Bn * Sn, Dn);
  k_attn_par<<<dim3(Bn, 7), dim3(256), ATTN_SMEM, stream>>>(x, wprev, w1W, w1b, w2W, w2b, aligned);
  k_cumsetup<<<dim3(1), dim3(256), 0, stream>>>(betas, difft, tscale, sa, sb, tsv);
  k_noisy_t<<<dim3(Bn, 7), dim3(256), 0, stream>>>(aligned, noise, sa, sb, xnT);
  k_diff_mfma<<<dim3(4, 4, Bn), dim3(256), 0, stream>>>(Wd_bf, xnT, tsv, aligned, noise, pn, genx_bf);
  k_gemm_bf16<<<dim3(200, 12), dim3(256), 0, stream>>>(genx_bf, Wih_bf, bih, xp, Bn * Sn, G3);
  k_gru_g<<<dim3(Bn), dim3(768), 0, stream>>>(xp, Wf16, bhh, wprev, (ushort*)nullptr);
  k_pool<<<dim3(Bn), dim3(256), 0, stream>>>(rnn, wlW, wlb, outW, outb, pred);
  k_pool<<<dim3(Bn), dim3(256), 0, stream>>>(wprev, wlW, wlb, outW, outb, gpred);
  (void)hipMemcpyAsync(out_noise, noise, NX * sizeof(float), hipMemcpyDeviceToDevice, stream);
}